// Round 1
// baseline (159.907 us; speedup 1.0000x reference)
//
#include <hip/hip_runtime.h>

// Problem constants
#define NB 2
#define NG 1024
#define HEIGHT 128
#define WIDTH 128
#define HW (HEIGHT * WIDTH)
#define NSEG 4
#define SEGLEN (NG / NSEG)

// ws layout (floats):
// [0..7]   accumulators: 0=l1_rgb_sum, 1=ssim_sum, 2=l1_depth_sum, 3=opac_sum
// [16 ..)  unsorted fields: 10 arrays of NB*NG
// then     sorted fields:   10 arrays of NB*NG
// then     rgb image: NB*3*HW
#define ACC_OFF 0
#define U_OFF 16
#define S_OFF (U_OFF + 10 * NB * NG)
#define RGB_OFF (S_OFF + 10 * NB * NG)
// fields: 0=z 1=px 2=py 3=i00 4=i01 5=i11 6=c0 7=c1 8=c2 9=op

__device__ inline float blk_reduce(float v, float* sh) {
    // full-wave reduce (64 lanes)
    for (int off = 32; off > 0; off >>= 1) v += __shfl_down(v, off, 64);
    int lane = threadIdx.x & 63;
    int w = threadIdx.x >> 6;
    __syncthreads();
    if (lane == 0) sh[w] = v;
    __syncthreads();
    float s = 0.f;
    if (threadIdx.x == 0) {
        int nw = (blockDim.x + 63) >> 6;
        for (int i = 0; i < nw; i++) s += sh[i];
    }
    return s;  // valid on thread 0 only
}

__global__ void k_init(float* ws) {
    if (threadIdx.x < 16) ws[ACC_OFF + threadIdx.x] = 0.f;
}

__global__ __launch_bounds__(256) void k_pre(const float* __restrict__ g,
                                             const float* __restrict__ intr,
                                             float* __restrict__ ws) {
    __shared__ float sh[4];
    int idx = blockIdx.x * 256 + threadIdx.x;  // 0..2047 exact
    int b = idx / NG;
    const float* row = g + (size_t)idx * 38;
    float mx = row[0], my = row[1], mz = row[2];
    float sx = row[3], sy = row[4], sz = row[5];
    float qw = row[6], qx = row[7], qy = row[8], qz = row[9];
    float op = row[10];
    float sh0 = row[11], sh1 = row[12], sh2 = row[13];
    float fx = intr[b * 9 + 0], fy = intr[b * 9 + 4];
    float cx = intr[b * 9 + 2], cy = intr[b * 9 + 5];

    float z = fmaxf(mz, 1e-4f);
    float px = fx * mx / z + cx;
    float py = fy * my / z + cy;

    // quat -> rot (as-is, not renormalized; matches reference)
    float r00 = 1.f - 2.f * (qy * qy + qz * qz), r01 = 2.f * (qx * qy - qw * qz), r02 = 2.f * (qx * qz + qw * qy);
    float r10 = 2.f * (qx * qy + qw * qz), r11 = 1.f - 2.f * (qx * qx + qz * qz), r12 = 2.f * (qy * qz - qw * qx);
    float r20 = 2.f * (qx * qz - qw * qy), r21 = 2.f * (qy * qz + qw * qx), r22 = 1.f - 2.f * (qx * qx + qy * qy);
    // RS = R * diag(s) ; cov3d = RS RS^T
    float a00 = r00 * sx, a01 = r01 * sy, a02 = r02 * sz;
    float a10 = r10 * sx, a11 = r11 * sy, a12 = r12 * sz;
    float a20 = r20 * sx, a21 = r21 * sy, a22 = r22 * sz;
    float m00 = a00 * a00 + a01 * a01 + a02 * a02;
    float m01 = a00 * a10 + a01 * a11 + a02 * a12;
    float m02 = a00 * a20 + a01 * a21 + a02 * a22;
    float m11 = a10 * a10 + a11 * a11 + a12 * a12;
    float m12 = a10 * a20 + a11 * a21 + a12 * a22;
    float m22 = a20 * a20 + a21 * a21 + a22 * a22;

    float zc = fmaxf(mz, 1e-6f);
    float aJ = fx / zc, bJ = -fx * mx / (zc * zc);
    float cJ = fy / zc, dJ = -fy * my / (zc * zc);
    float c00 = aJ * aJ * m00 + 2.f * aJ * bJ * m02 + bJ * bJ * m22 + 0.3f;
    float c01 = cJ * (aJ * m01 + bJ * m12) + dJ * (aJ * m02 + bJ * m22);
    float c11 = cJ * cJ * m11 + 2.f * cJ * dJ * m12 + dJ * dJ * m22 + 0.3f;
    float det = fmaxf(c00 * c11 - c01 * c01, 1e-8f);
    float i00 = c11 / det;
    float i11 = c00 / det;
    float i01 = -c01 / det;

    const float C0c = 0.28209479177387814f;
    float col0 = fminf(fmaxf(sh0 * C0c + 0.5f, 0.f), 1.f);
    float col1 = fminf(fmaxf(sh1 * C0c + 0.5f, 0.f), 1.f);
    float col2 = fminf(fmaxf(sh2 * C0c + 0.5f, 0.f), 1.f);

    float* u = ws + U_OFF;
    const int S = NB * NG;
    u[0 * S + idx] = z;
    u[1 * S + idx] = px;
    u[2 * S + idx] = py;
    u[3 * S + idx] = i00;
    u[4 * S + idx] = i01;
    u[5 * S + idx] = i11;
    u[6 * S + idx] = col0;
    u[7 * S + idx] = col1;
    u[8 * S + idx] = col2;
    u[9 * S + idx] = op;

    // opacity entropy regularizer
    float o = fminf(fmaxf(op, 1e-6f), 1.f - 1e-6f);
    float ent = -(o * logf(o) + (1.f - o) * logf(1.f - o));
    float s = blk_reduce(ent, sh);
    if (threadIdx.x == 0) atomicAdd(ws + ACC_OFF + 3, s);
}

__global__ __launch_bounds__(1024) void k_sort(float* __restrict__ ws) {
    __shared__ float zsh[NG];
    int b = blockIdx.x;
    int i = threadIdx.x;
    const int S = NB * NG;
    float* u = ws + U_OFF;
    float* s = ws + S_OFF;
    float zi = u[0 * S + b * NG + i];
    zsh[i] = zi;
    __syncthreads();
    int rank = 0;
    for (int j = 0; j < NG; j++) {
        float zj = zsh[j];
        rank += (zj < zi) || (zj == zi && j < i);
    }
#pragma unroll
    for (int f = 0; f < 10; f++) s[f * S + b * NG + rank] = u[f * S + b * NG + i];
}

__global__ __launch_bounds__(256) void k_render(const float* __restrict__ tgt_d,
                                                float* __restrict__ ws) {
    __shared__ float sg[10][NG];    // 40 KB staged sorted gaussians for this batch
    __shared__ float comb[5][256];  // segment partials: T, r, g, b, d
    int tid = threadIdx.x;
    int lane = tid & 63;
    int seg = tid >> 6;
    int blk = blockIdx.x;       // 512 blocks
    int b = blk >> 8;           // 256 tiles per batch
    int tile = blk & 255;
    int p = tile * 64 + lane;   // pixel index in [0, HW)
    int y = p >> 7, x = p & 127;

    const int S = NB * NG;
    const float* s = ws + S_OFF + b * NG;
#pragma unroll
    for (int f = 0; f < 10; f++) {
        for (int k = tid; k < NG; k += 256) sg[f][k] = s[f * S + k];
    }
    __syncthreads();

    float xf = (float)x, yf = (float)y;
    float T = 1.f, cr = 0.f, cg = 0.f, cb = 0.f, cd = 0.f;
    int base = seg * SEGLEN;
    for (int k = 0; k < SEGLEN; k++) {
        int j = base + k;
        float dx = xf - sg[1][j];
        float dy = yf - sg[2][j];
        float q = sg[3][j] * dx * dx + 2.f * sg[4][j] * dx * dy + sg[5][j] * dy * dy;
        float pw = fminf(fmaxf(-0.5f * q, -10.f), 0.f);
        float a = __expf(pw) * sg[9][j];
        a = fminf(a, 0.99f);
        float w = T * a;
        cr += w * sg[6][j];
        cg += w * sg[7][j];
        cb += w * sg[8][j];
        cd += w * sg[0][j];
        T *= (1.f - a);
    }
    comb[0][tid] = T;
    comb[1][tid] = cr;
    comb[2][tid] = cg;
    comb[3][tid] = cb;
    comb[4][tid] = cd;
    __syncthreads();

    if (tid < 64) {
        float T0 = comb[0][tid], r0 = comb[1][tid], g0 = comb[2][tid];
        float b0 = comb[3][tid], d0 = comb[4][tid];
#pragma unroll
        for (int sgi = 1; sgi < NSEG; sgi++) {
            int j = sgi * 64 + tid;
            r0 += T0 * comb[1][j];
            g0 += T0 * comb[2][j];
            b0 += T0 * comb[3][j];
            d0 += T0 * comb[4][j];
            T0 *= comb[0][j];
        }
        r0 = fminf(fmaxf(r0, 0.f), 1.f);
        g0 = fminf(fmaxf(g0, 0.f), 1.f);
        b0 = fminf(fmaxf(b0, 0.f), 1.f);
        float* rgb = ws + RGB_OFF;
        rgb[((b * 3 + 0) * HEIGHT + y) * WIDTH + x] = r0;
        rgb[((b * 3 + 1) * HEIGHT + y) * WIDTH + x] = g0;
        rgb[((b * 3 + 2) * HEIGHT + y) * WIDTH + x] = b0;
        float l1d = fabsf(d0 - tgt_d[(b * HEIGHT + y) * WIDTH + x]);
        for (int off = 32; off > 0; off >>= 1) l1d += __shfl_down(l1d, off, 64);
        if (tid == 0) atomicAdd(ws + ACC_OFF + 2, l1d);
    }
}

__global__ __launch_bounds__(256) void k_ssim(const float* __restrict__ tgt_rgb,
                                              float* __restrict__ ws) {
    __shared__ float sh[4];
    int idx = blockIdx.x * 256 + threadIdx.x;  // < 98304 exact
    const float* img1 = ws + RGB_OFF;
    int bc = idx >> 14;       // plane index in [0, 6)
    int pix = idx & (HW - 1);
    int y = pix >> 7, x = pix & 127;

    // 7x7 normalized gaussian window (sigma=1.5)
    float gg[7];
    float gs = 0.f;
#pragma unroll
    for (int i = 0; i < 7; i++) {
        float c = (float)(i - 3);
        gg[i] = __expf(-c * c / 4.5f);
        gs += gg[i];
    }
#pragma unroll
    for (int i = 0; i < 7; i++) gg[i] /= gs;

    float mu1 = 0.f, mu2 = 0.f, s11 = 0.f, s22 = 0.f, s12 = 0.f;
    int plane = bc * HW;
#pragma unroll
    for (int dy = -3; dy <= 3; dy++) {
        int yy = y + dy;
#pragma unroll
        for (int dx = -3; dx <= 3; dx++) {
            int xx = x + dx;
            float w = gg[dy + 3] * gg[dx + 3];
            float i1 = 0.f, i2 = 0.f;
            if (yy >= 0 && yy < HEIGHT && xx >= 0 && xx < WIDTH) {
                int o = plane + yy * WIDTH + xx;
                i1 = img1[o];
                i2 = tgt_rgb[o];
            }
            mu1 += w * i1;
            mu2 += w * i2;
            s11 += w * i1 * i1;
            s22 += w * i2 * i2;
            s12 += w * i1 * i2;
        }
    }
    float v1 = s11 - mu1 * mu1;
    float v2 = s22 - mu2 * mu2;
    float cv = s12 - mu1 * mu2;
    const float C1 = 1e-4f, C2 = 9e-4f;
    float ssim = ((2.f * mu1 * mu2 + C1) * (2.f * cv + C2)) /
                 ((mu1 * mu1 + mu2 * mu2 + C1) * (v1 + v2 + C2));
    float l1 = fabsf(img1[idx] - tgt_rgb[idx]);

    float s_ssim = blk_reduce(ssim, sh);
    float s_l1 = blk_reduce(l1, sh);
    if (threadIdx.x == 0) {
        atomicAdd(ws + ACC_OFF + 1, s_ssim);
        atomicAdd(ws + ACC_OFF + 0, s_l1);
    }
}

__global__ void k_final(const float* __restrict__ ws, float* __restrict__ out) {
    float l1r = ws[ACC_OFF + 0] / (float)(NB * 3 * HW);
    float ssim = ws[ACC_OFF + 1] / (float)(NB * 3 * HW);
    float l1d = ws[ACC_OFF + 2] / (float)(NB * HW);
    float opa = ws[ACC_OFF + 3] / (float)(NB * NG);
    out[0] = 0.8f * l1r + 0.2f * (1.f - ssim) + 0.5f * l1d + 0.01f * opa;
}

extern "C" void kernel_launch(void* const* d_in, const int* in_sizes, int n_in,
                              void* d_out, int out_size, void* d_ws, size_t ws_size,
                              hipStream_t stream) {
    const float* g = (const float*)d_in[0];
    const float* intr = (const float*)d_in[1];
    const float* trgb = (const float*)d_in[2];
    const float* tdep = (const float*)d_in[3];
    float* ws = (float*)d_ws;
    float* out = (float*)d_out;

    hipLaunchKernelGGL(k_init, dim3(1), dim3(64), 0, stream, ws);
    hipLaunchKernelGGL(k_pre, dim3((NB * NG) / 256), dim3(256), 0, stream, g, intr, ws);
    hipLaunchKernelGGL(k_sort, dim3(NB), dim3(NG), 0, stream, ws);
    hipLaunchKernelGGL(k_render, dim3((NB * HW) / 64), dim3(256), 0, stream, tdep, ws);
    hipLaunchKernelGGL(k_ssim, dim3((NB * 3 * HW) / 256), dim3(256), 0, stream, trgb, ws);
    hipLaunchKernelGGL(k_final, dim3(1), dim3(1), 0, stream, ws, out);
}